// Round 1
// baseline (791.569 us; speedup 1.0000x reference)
//
#include <hip/hip_runtime.h>
#include <math.h>

#define M_ANCH   589824
#define NCLS     80
#define TOPK_N   1000
#define NBINS    65536
#define CAND_CAP 4096

#define SCALE_CLAMP_F 4.135166556742356f   /* log(1000/16) as f32 */
#define INV_IMG       (1.0f/2048.0f)

// ---------------- ws layout (bytes) ----------------
// [0,       262144)   hist (65536 u32)        -- memset 0
// [262144,  262148)   cand count (u32)        -- memset 0
// [262148,  262152)   gather bin (u32)        -- memset 0
// [262400,  295168)   cand keys (4096 u64)
// [295168,  303168)   topkeys (1000 u64)
// [303168,  319168)   boxes (1000 float4)
// [319168,  323168)   labels (1000 i32)
// [323168,  327168)   valid (1000 i32)
// [327168,  455168)   sup matrix (1000*16 u64)
// [455168,  2814464)  mkeys (589824 u32)
// total ~2.7 MB
#define WS_HIST    0
#define WS_CNT     262144
#define WS_GBIN    262148
#define WS_CAND    262400
#define WS_TOPK    295168
#define WS_BOXES   303168
#define WS_LABELS  319168
#define WS_VALID   323168
#define WS_SUP     327168
#define WS_MKEYS   455168

// monotone float->uint map (positive floats get top bit set)
__device__ __forceinline__ unsigned fmap(unsigned b) {
    return (b & 0x80000000u) ? ~b : (b | 0x80000000u);
}
__device__ __forceinline__ unsigned funmap(unsigned k) {
    return (k & 0x80000000u) ? (k ^ 0x80000000u) : ~k;
}

// K1: per-anchor max logit -> mapped key + histogram
__global__ __launch_bounds__(256) void k_rowmax(const float* __restrict__ cls,
                                                unsigned* __restrict__ mkeys,
                                                unsigned* __restrict__ hist) {
    int i = blockIdx.x * blockDim.x + threadIdx.x;
    if (i >= M_ANCH) return;
    const float4* r4 = (const float4*)(cls + (size_t)i * NCLS);
    float m = -INFINITY;
#pragma unroll
    for (int c = 0; c < NCLS / 4; ++c) {
        float4 v = r4[c];
        m = fmaxf(m, fmaxf(fmaxf(v.x, v.y), fmaxf(v.z, v.w)));
    }
    unsigned key = fmap(__float_as_uint(m));
    mkeys[i] = key;
    atomicAdd(&hist[key >> 16], 1u);
}

// K2: find histogram bin of the 1000th largest; gather threshold = bin-1
__global__ __launch_bounds__(256) void k_findbin(const unsigned* __restrict__ hist,
                                                 unsigned* __restrict__ gbin) {
    __shared__ unsigned csum[256];
    int t = threadIdx.x;
    unsigned s = 0;
    const unsigned* h = hist + t * 256;
    for (int k = 0; k < 256; ++k) s += h[k];
    csum[t] = s;
    __syncthreads();
    if (t == 0) {
        unsigned cum = 0, above = 0;
        int chunk = 0;
        for (int c = 255; c >= 0; --c) {
            if (cum + csum[c] >= TOPK_N || c == 0) { chunk = c; above = cum; break; }
            cum += csum[c];
        }
        unsigned cum2 = above;
        int B = chunk * 256;
        for (int b = chunk * 256 + 255; b >= chunk * 256; --b) {
            cum2 += hist[b];
            if (cum2 >= TOPK_N) { B = b; break; }
            if (b == chunk * 256) B = b;
        }
        *gbin = (B >= 1) ? (unsigned)(B - 1) : 0u;
    }
}

// K3: gather candidates above threshold as (score_bits<<32)|~idx
__global__ __launch_bounds__(256) void k_gather(const unsigned* __restrict__ mkeys,
                                                const unsigned* __restrict__ gbin,
                                                unsigned* __restrict__ cnt,
                                                unsigned long long* __restrict__ cand) {
    int i = blockIdx.x * blockDim.x + threadIdx.x;
    if (i >= M_ANCH) return;
    unsigned gb = *gbin;
    unsigned key = mkeys[i];
    if ((key >> 16) >= gb) {
        unsigned pos = atomicAdd(cnt, 1u);
        if (pos < CAND_CAP) {
            float m = __uint_as_float(funmap(key));
            // emulate np float32 sigmoid pipeline with correctly-rounded exp:
            float e = (float)exp(-(double)m);
            float sc = 1.0f / (1.0f + e);
            unsigned sb = __float_as_uint(sc);
            cand[pos] = ((unsigned long long)sb << 32) | (unsigned)(~(unsigned)i);
        }
    }
}

// K4: bitonic sort (descending) of up to 4096 candidate keys in LDS
__global__ __launch_bounds__(1024) void k_sort(const unsigned* __restrict__ cnt,
                                               const unsigned long long* __restrict__ cand,
                                               unsigned long long* __restrict__ topkeys) {
    __shared__ unsigned long long sh[CAND_CAP];
    int t = threadIdx.x;
    unsigned n = *cnt;
    if (n > CAND_CAP) n = CAND_CAP;
    for (int k = t; k < CAND_CAP; k += 1024) sh[k] = (k < (int)n) ? cand[k] : 0ull;
    __syncthreads();
    for (int size = 2; size <= CAND_CAP; size <<= 1) {
        for (int stride = size >> 1; stride > 0; stride >>= 1) {
            for (int i = t; i < CAND_CAP; i += 1024) {
                int j = i ^ stride;
                if (j > i) {
                    unsigned long long a = sh[i], b = sh[j];
                    bool seg = ((i & size) == 0);
                    bool sw = seg ? (a < b) : (a > b);   // descending overall
                    if (sw) { sh[i] = b; sh[j] = a; }
                }
            }
            __syncthreads();
        }
    }
    for (int k = t; k < TOPK_N; k += 1024) topkeys[k] = sh[k];
}

// K5: decode boxes, labels, scores for the top-1000
__global__ __launch_bounds__(256) void k_final(const unsigned long long* __restrict__ topkeys,
                                               const float* __restrict__ cls,
                                               const float* __restrict__ reg,
                                               const float* __restrict__ anch,
                                               float* __restrict__ out,
                                               float4* __restrict__ boxes_ws,
                                               int* __restrict__ lab_ws,
                                               int* __restrict__ val_ws) {
    int r = blockIdx.x * blockDim.x + threadIdx.x;
    if (r >= TOPK_N) return;
    unsigned long long key = topkeys[r];
    unsigned idx = ~(unsigned)(key & 0xFFFFFFFFull);
    float sc = __uint_as_float((unsigned)(key >> 32));
    // label = argmax (first max wins, matching np.argmax)
    const float* row = cls + (size_t)idx * NCLS;
    float best = -INFINITY;
    int lbl = 0;
    for (int c = 0; c < NCLS; ++c) {
        float v = row[c];
        if (v > best) { best = v; lbl = c; }
    }
    float4 rg = ((const float4*)reg)[idx];
    float4 an = ((const float4*)anch)[idx];
    float ox = fminf(fmaxf(rg.x * an.z, -32.0f), 32.0f);
    float oy = fminf(fmaxf(rg.y * an.w, -32.0f), 32.0f);
    float cx = an.x + ox, cy = an.y + oy;
    float w = an.z * expf(fminf(rg.z, SCALE_CLAMP_F));
    float h = an.w * expf(fminf(rg.w, SCALE_CLAMP_F));
    float x1 = fminf(fmaxf((cx - 0.5f * w) * INV_IMG, 0.0f), 1.0f);
    float y1 = fminf(fmaxf((cy - 0.5f * h) * INV_IMG, 0.0f), 1.0f);
    float x2 = fminf(fmaxf((cx + 0.5f * w) * INV_IMG, 0.0f), 1.0f);
    float y2 = fminf(fmaxf((cy + 0.5f * h) * INV_IMG, 0.0f), 1.0f);
    out[r * 4 + 0] = x1;
    out[r * 4 + 1] = y1;
    out[r * 4 + 2] = x2;
    out[r * 4 + 3] = y2;
    out[4 * TOPK_N + r] = sc;
    out[5 * TOPK_N + r] = (float)lbl;
    boxes_ws[r] = make_float4(x1, y1, x2, y2);
    lab_ws[r] = lbl;
    val_ws[r] = (sc >= 0.05f) ? 1 : 0;
}

// K6: suppression bitmask matrix, row i = 16 u64 words over j
__global__ __launch_bounds__(64) void k_sup(const float4* __restrict__ boxes,
                                            const int* __restrict__ labs,
                                            unsigned long long* __restrict__ sup) {
    int i = blockIdx.x;
    int lane = threadIdx.x;
    float4 bi = boxes[i];
    float ai = (bi.z - bi.x) * (bi.w - bi.y);
    int li = labs[i];
#pragma unroll
    for (int c = 0; c < 16; ++c) {
        int j = c * 64 + lane;
        bool bit = false;
        if (j < TOPK_N) {
            float4 bj = boxes[j];
            float aj = (bj.z - bj.x) * (bj.w - bj.y);
            float xx1 = fmaxf(bi.x, bj.x), yy1 = fmaxf(bi.y, bj.y);
            float xx2 = fminf(bi.z, bj.z), yy2 = fminf(bi.w, bj.w);
            float w = fmaxf(1e-10f, xx2 - xx1);
            float h = fmaxf(1e-10f, yy2 - yy1);
            float inter = w * h;
            float iou = inter / (ai + aj - inter + 1e-10f);
            bit = (iou > 0.6f) && (labs[j] == li);
        }
        unsigned long long ball = __ballot(bit);
        if (lane == 0) sup[(size_t)i * 16 + c] = ball;
    }
}

// K7: exact greedy NMS resolve, single wave, 64-box chunks
__global__ __launch_bounds__(64) void k_nms(const unsigned long long* __restrict__ sup,
                                            const int* __restrict__ val,
                                            float* __restrict__ out_keep) {
    int lane = threadIdx.x;
    unsigned long long kw[16];
#pragma unroll
    for (int c = 0; c < 16; ++c) kw[c] = 0ull;
    unsigned long long lowmask = (lane == 0) ? 0ull : (~0ull >> (64 - lane));
    for (int c = 0; c < 16; ++c) {
        int b = c * 64 + lane;
        bool v = false;
        bool ext = false;
        unsigned long long m = 0ull;
        if (b < TOPK_N) {
            v = (val[b] != 0);
            const unsigned long long* rowp = sup + (size_t)b * 16;
            for (int w = 0; w < c; ++w) ext = ext || ((rowp[w] & kw[w]) != 0ull);
            m = rowp[c];
        }
        bool mykeep = false;
        for (int i = 0; i < 64; ++i) {
            unsigned long long ball = __ballot(mykeep);
            if (lane == i) {
                mykeep = v && !ext && ((ball & m & lowmask) == 0ull);
            }
        }
        unsigned long long ball = __ballot(mykeep);
        kw[c] = ball;
        if (b < TOPK_N) out_keep[b] = ((ball >> lane) & 1ull) ? 1.0f : 0.0f;
    }
}

extern "C" void kernel_launch(void* const* d_in, const int* in_sizes, int n_in,
                              void* d_out, int out_size, void* d_ws, size_t ws_size,
                              hipStream_t stream) {
    const float* cls  = (const float*)d_in[0];
    const float* reg  = (const float*)d_in[1];
    const float* anch = (const float*)d_in[2];
    float* out = (float*)d_out;
    char* ws = (char*)d_ws;

    unsigned* hist = (unsigned*)(ws + WS_HIST);
    unsigned* cnt  = (unsigned*)(ws + WS_CNT);
    unsigned* gbin = (unsigned*)(ws + WS_GBIN);
    unsigned long long* cand    = (unsigned long long*)(ws + WS_CAND);
    unsigned long long* topkeys = (unsigned long long*)(ws + WS_TOPK);
    float4* boxes = (float4*)(ws + WS_BOXES);
    int* labs     = (int*)(ws + WS_LABELS);
    int* valid    = (int*)(ws + WS_VALID);
    unsigned long long* sup = (unsigned long long*)(ws + WS_SUP);
    unsigned* mkeys = (unsigned*)(ws + WS_MKEYS);

    // zero histogram + counters
    hipMemsetAsync(ws, 0, WS_CAND, stream);

    k_rowmax<<<M_ANCH / 256, 256, 0, stream>>>(cls, mkeys, hist);
    k_findbin<<<1, 256, 0, stream>>>(hist, gbin);
    k_gather<<<M_ANCH / 256, 256, 0, stream>>>(mkeys, gbin, cnt, cand);
    k_sort<<<1, 1024, 0, stream>>>(cnt, cand, topkeys);
    k_final<<<4, 256, 0, stream>>>(topkeys, cls, reg, anch, out, boxes, labs, valid);
    k_sup<<<TOPK_N, 64, 0, stream>>>(boxes, labs, sup);
    k_nms<<<1, 64, 0, stream>>>(sup, valid, out + 6 * TOPK_N);
}

// Round 2
// 402.410 us; speedup vs baseline: 1.9671x; 1.9671x over previous
//
#include <hip/hip_runtime.h>
#include <math.h>

#define M_ANCH   589824
#define NCLS     80
#define TOPK_N   1000
#define CAND_CAP 4096
#define NREP     64

#define SCALE_CLAMP_F 4.135166556742356f   /* log(1000/16) as f32 */
#define INV_IMG       (1.0f/2048.0f)

// ---------------- ws layout (bytes) ----------------
// [0,      65536)   hist1 replicas (64 x 256 u32)   -- memset 0
// [65536, 131072)   hist2 replicas (64 x 256 u32)   -- memset 0
// [131072,131076)   cand count (u32)                -- memset 0
// [131076,131084)   sel (C1, above1)                -- memset 0
// [131084,131088)   gbin (u32)                      -- memset 0
// [131328,164096)   cand keys (4096 u64)
// [164096,172096)   topkeys (1000 u64)
// [172096,188096)   boxes (1000 float4)
// [188096,192096)   labels (1000 i32)
// [192096,196096)   valid (1000 i32)
// [196096,324096)   sup matrix (1000*16 u64)
// [324096,2683392)  mkeys (589824 u32)
#define WS_H1R     0
#define WS_H2R     65536
#define WS_CNT     131072
#define WS_SEL     131076
#define WS_GBIN    131084
#define WS_MEMSET  131088
#define WS_CAND    131328
#define WS_TOPK    164096
#define WS_BOXES   172096
#define WS_LABELS  188096
#define WS_VALID   192096
#define WS_SUP     196096
#define WS_MKEYS   324096

// monotone float->uint map (positive floats get top bit set)
__device__ __forceinline__ unsigned fmap(unsigned b) {
    return (b & 0x80000000u) ? ~b : (b | 0x80000000u);
}
__device__ __forceinline__ unsigned funmap(unsigned k) {
    return (k & 0x80000000u) ? (k ^ 0x80000000u) : ~k;
}

// K1: per-anchor max logit -> mapped key; coarse (top byte) LDS histogram,
// flushed to 64 replicated global histograms to kill atomic hotspots.
__global__ __launch_bounds__(256) void k_rowmax(const float* __restrict__ cls,
                                                unsigned* __restrict__ mkeys,
                                                unsigned* __restrict__ h1r) {
    __shared__ unsigned lh[256];
    int t = threadIdx.x;
    lh[t] = 0;
    __syncthreads();
    int lane = t & 63, w = t >> 6;
    int part = lane & 3;                 // 4 lanes per row, 20 floats each
    int rsub = (w << 4) + (lane >> 2);   // 0..63 row-within-iteration
#pragma unroll
    for (int it = 0; it < 4; ++it) {
        int row = blockIdx.x * 256 + it * 64 + rsub;
        const float4* p = (const float4*)(cls + (size_t)row * NCLS) + part * 5;
        float m = -INFINITY;
#pragma unroll
        for (int i = 0; i < 5; ++i) {
            float4 v = p[i];
            m = fmaxf(m, fmaxf(fmaxf(v.x, v.y), fmaxf(v.z, v.w)));
        }
        m = fmaxf(m, __shfl_xor(m, 1));
        m = fmaxf(m, __shfl_xor(m, 2));
        if (part == 0) {
            unsigned key = fmap(__float_as_uint(m));
            mkeys[row] = key;
            atomicAdd(&lh[key >> 24], 1u);
        }
    }
    __syncthreads();
    unsigned c = lh[t];
    if (c) atomicAdd(&h1r[((blockIdx.x & (NREP - 1)) << 8) + t], c);
}

// K2: pick coarse bin C1 (largest byte with cum-from-top >= TOPK), record
// count strictly above it.
__global__ __launch_bounds__(256) void k_find1(const unsigned* __restrict__ h1r,
                                               unsigned* __restrict__ sel) {
    __shared__ unsigned h[256];
    int t = threadIdx.x;
    unsigned s = 0;
    for (int r = 0; r < NREP; ++r) s += h1r[(r << 8) + t];
    h[t] = s;
    __syncthreads();
    if (t == 0) {
        unsigned cum = 0, above = 0;
        int C = 0;
        for (int c = 255; c >= 0; --c) {
            if (cum + h[c] >= TOPK_N || c == 0) { C = c; above = cum; break; }
            cum += h[c];
        }
        sel[0] = (unsigned)C;
        sel[1] = above;
    }
}

// K3: second-byte histogram restricted to keys whose top byte == C1.
__global__ __launch_bounds__(256) void k_hist2(const unsigned* __restrict__ mkeys,
                                               const unsigned* __restrict__ sel,
                                               unsigned* __restrict__ h2r) {
    __shared__ unsigned lh[256];
    int t = threadIdx.x;
    lh[t] = 0;
    __syncthreads();
    unsigned C1 = sel[0];
    int i = blockIdx.x * 256 + t;
    unsigned key = mkeys[i];
    if ((key >> 24) == C1) atomicAdd(&lh[(key >> 16) & 0xFFu], 1u);
    __syncthreads();
    unsigned c = lh[t];
    if (c) atomicAdd(&h2r[((blockIdx.x & (NREP - 1)) << 8) + t], c);
}

// K4: reconstruct the exact 16-bit bin boundary B; gather threshold = B-1.
__global__ __launch_bounds__(256) void k_find2(const unsigned* __restrict__ h2r,
                                               const unsigned* __restrict__ sel,
                                               unsigned* __restrict__ gbin) {
    __shared__ unsigned h[256];
    int t = threadIdx.x;
    unsigned s = 0;
    for (int r = 0; r < NREP; ++r) s += h2r[(r << 8) + t];
    h[t] = s;
    __syncthreads();
    if (t == 0) {
        unsigned cum = sel[1];
        int B = (int)(sel[0] << 8);
        for (int f = 255; f >= 0; --f) {
            cum += h[f];
            if (cum >= TOPK_N) { B = (int)((sel[0] << 8) | (unsigned)f); break; }
        }
        *gbin = (B >= 1) ? (unsigned)(B - 1) : 0u;
    }
}

// K5: gather candidates above threshold as (score_bits<<32)|~idx
__global__ __launch_bounds__(256) void k_gather(const unsigned* __restrict__ mkeys,
                                                const unsigned* __restrict__ gbin,
                                                unsigned* __restrict__ cnt,
                                                unsigned long long* __restrict__ cand) {
    int i = blockIdx.x * blockDim.x + threadIdx.x;
    if (i >= M_ANCH) return;
    unsigned gb = *gbin;
    unsigned key = mkeys[i];
    if ((key >> 16) >= gb) {
        unsigned pos = atomicAdd(cnt, 1u);
        if (pos < CAND_CAP) {
            float m = __uint_as_float(funmap(key));
            // emulate np float32 sigmoid pipeline with correctly-rounded exp:
            float e = (float)exp(-(double)m);
            float sc = 1.0f / (1.0f + e);
            unsigned sb = __float_as_uint(sc);
            cand[pos] = ((unsigned long long)sb << 32) | (unsigned)(~(unsigned)i);
        }
    }
}

// K6: bitonic sort (descending), sized to next pow2 of candidate count.
__global__ __launch_bounds__(1024) void k_sort(const unsigned* __restrict__ cnt,
                                               const unsigned long long* __restrict__ cand,
                                               unsigned long long* __restrict__ topkeys) {
    __shared__ unsigned long long sh[CAND_CAP];
    int t = threadIdx.x;
    unsigned n = *cnt;
    if (n > CAND_CAP) n = CAND_CAP;
    int np = 1024;
    while (np < (int)n) np <<= 1;        // n >= 1000 by construction
    for (int k = t; k < np; k += 1024) sh[k] = (k < (int)n) ? cand[k] : 0ull;
    __syncthreads();
    for (int size = 2; size <= np; size <<= 1) {
        for (int stride = size >> 1; stride > 0; stride >>= 1) {
            for (int i = t; i < np; i += 1024) {
                int j = i ^ stride;
                if (j > i) {
                    unsigned long long a = sh[i], b = sh[j];
                    bool seg = ((i & size) == 0);
                    bool sw = seg ? (a < b) : (a > b);   // descending overall
                    if (sw) { sh[i] = b; sh[j] = a; }
                }
            }
            __syncthreads();
        }
    }
    if (t < TOPK_N) topkeys[t] = sh[t];
}

// K7: decode boxes, labels, scores for the top-1000
__global__ __launch_bounds__(256) void k_final(const unsigned long long* __restrict__ topkeys,
                                               const float* __restrict__ cls,
                                               const float* __restrict__ reg,
                                               const float* __restrict__ anch,
                                               float* __restrict__ out,
                                               float4* __restrict__ boxes_ws,
                                               int* __restrict__ lab_ws,
                                               int* __restrict__ val_ws) {
    int r = blockIdx.x * blockDim.x + threadIdx.x;
    if (r >= TOPK_N) return;
    unsigned long long key = topkeys[r];
    unsigned idx = ~(unsigned)(key & 0xFFFFFFFFull);
    float sc = __uint_as_float((unsigned)(key >> 32));
    // label = argmax (first max wins, matching np.argmax)
    const float* row = cls + (size_t)idx * NCLS;
    float best = -INFINITY;
    int lbl = 0;
    for (int c = 0; c < NCLS; ++c) {
        float v = row[c];
        if (v > best) { best = v; lbl = c; }
    }
    float4 rg = ((const float4*)reg)[idx];
    float4 an = ((const float4*)anch)[idx];
    float ox = fminf(fmaxf(rg.x * an.z, -32.0f), 32.0f);
    float oy = fminf(fmaxf(rg.y * an.w, -32.0f), 32.0f);
    float cx = an.x + ox, cy = an.y + oy;
    float w = an.z * expf(fminf(rg.z, SCALE_CLAMP_F));
    float h = an.w * expf(fminf(rg.w, SCALE_CLAMP_F));
    float x1 = fminf(fmaxf((cx - 0.5f * w) * INV_IMG, 0.0f), 1.0f);
    float y1 = fminf(fmaxf((cy - 0.5f * h) * INV_IMG, 0.0f), 1.0f);
    float x2 = fminf(fmaxf((cx + 0.5f * w) * INV_IMG, 0.0f), 1.0f);
    float y2 = fminf(fmaxf((cy + 0.5f * h) * INV_IMG, 0.0f), 1.0f);
    out[r * 4 + 0] = x1;
    out[r * 4 + 1] = y1;
    out[r * 4 + 2] = x2;
    out[r * 4 + 3] = y2;
    out[4 * TOPK_N + r] = sc;
    out[5 * TOPK_N + r] = (float)lbl;
    boxes_ws[r] = make_float4(x1, y1, x2, y2);
    lab_ws[r] = lbl;
    val_ws[r] = (sc >= 0.05f) ? 1 : 0;
}

// K8: suppression bitmask matrix, row i = 16 u64 words over j
__global__ __launch_bounds__(64) void k_sup(const float4* __restrict__ boxes,
                                            const int* __restrict__ labs,
                                            unsigned long long* __restrict__ sup) {
    int i = blockIdx.x;
    int lane = threadIdx.x;
    float4 bi = boxes[i];
    float ai = (bi.z - bi.x) * (bi.w - bi.y);
    int li = labs[i];
#pragma unroll
    for (int c = 0; c < 16; ++c) {
        int j = c * 64 + lane;
        bool bit = false;
        if (j < TOPK_N) {
            float4 bj = boxes[j];
            float aj = (bj.z - bj.x) * (bj.w - bj.y);
            float xx1 = fmaxf(bi.x, bj.x), yy1 = fmaxf(bi.y, bj.y);
            float xx2 = fminf(bi.z, bj.z), yy2 = fminf(bi.w, bj.w);
            float w = fmaxf(1e-10f, xx2 - xx1);
            float h = fmaxf(1e-10f, yy2 - yy1);
            float inter = w * h;
            float iou = inter / (ai + aj - inter + 1e-10f);
            bit = (iou > 0.6f) && (labs[j] == li);
        }
        unsigned long long ball = __ballot(bit);
        if (lane == 0) sup[(size_t)i * 16 + c] = ball;
    }
}

// K9: exact greedy NMS resolve, single wave, 64-box chunks
__global__ __launch_bounds__(64) void k_nms(const unsigned long long* __restrict__ sup,
                                            const int* __restrict__ val,
                                            float* __restrict__ out_keep) {
    int lane = threadIdx.x;
    unsigned long long kw[16];
#pragma unroll
    for (int c = 0; c < 16; ++c) kw[c] = 0ull;
    unsigned long long lowmask = (lane == 0) ? 0ull : (~0ull >> (64 - lane));
    for (int c = 0; c < 16; ++c) {
        int b = c * 64 + lane;
        bool v = false;
        bool ext = false;
        unsigned long long m = 0ull;
        if (b < TOPK_N) {
            v = (val[b] != 0);
            const unsigned long long* rowp = sup + (size_t)b * 16;
            for (int w = 0; w < c; ++w) ext = ext || ((rowp[w] & kw[w]) != 0ull);
            m = rowp[c];
        }
        bool mykeep = false;
        for (int i = 0; i < 64; ++i) {
            unsigned long long ball = __ballot(mykeep);
            if (lane == i) {
                mykeep = v && !ext && ((ball & m & lowmask) == 0ull);
            }
        }
        unsigned long long ball = __ballot(mykeep);
        kw[c] = ball;
        if (b < TOPK_N) out_keep[b] = ((ball >> lane) & 1ull) ? 1.0f : 0.0f;
    }
}

extern "C" void kernel_launch(void* const* d_in, const int* in_sizes, int n_in,
                              void* d_out, int out_size, void* d_ws, size_t ws_size,
                              hipStream_t stream) {
    const float* cls  = (const float*)d_in[0];
    const float* reg  = (const float*)d_in[1];
    const float* anch = (const float*)d_in[2];
    float* out = (float*)d_out;
    char* ws = (char*)d_ws;

    unsigned* h1r  = (unsigned*)(ws + WS_H1R);
    unsigned* h2r  = (unsigned*)(ws + WS_H2R);
    unsigned* cnt  = (unsigned*)(ws + WS_CNT);
    unsigned* sel  = (unsigned*)(ws + WS_SEL);
    unsigned* gbin = (unsigned*)(ws + WS_GBIN);
    unsigned long long* cand    = (unsigned long long*)(ws + WS_CAND);
    unsigned long long* topkeys = (unsigned long long*)(ws + WS_TOPK);
    float4* boxes = (float4*)(ws + WS_BOXES);
    int* labs     = (int*)(ws + WS_LABELS);
    int* valid    = (int*)(ws + WS_VALID);
    unsigned long long* sup = (unsigned long long*)(ws + WS_SUP);
    unsigned* mkeys = (unsigned*)(ws + WS_MKEYS);

    hipMemsetAsync(ws, 0, WS_MEMSET, stream);

    k_rowmax<<<M_ANCH / 256, 256, 0, stream>>>(cls, mkeys, h1r);
    k_find1 <<<1, 256, 0, stream>>>(h1r, sel);
    k_hist2 <<<M_ANCH / 256, 256, 0, stream>>>(mkeys, sel, h2r);
    k_find2 <<<1, 256, 0, stream>>>(h2r, sel, gbin);
    k_gather<<<M_ANCH / 256, 256, 0, stream>>>(mkeys, gbin, cnt, cand);
    k_sort  <<<1, 1024, 0, stream>>>(cnt, cand, topkeys);
    k_final <<<4, 256, 0, stream>>>(topkeys, cls, reg, anch, out, boxes, labs, valid);
    k_sup   <<<TOPK_N, 64, 0, stream>>>(boxes, labs, sup);
    k_nms   <<<1, 64, 0, stream>>>(sup, valid, out + 6 * TOPK_N);
}